// Round 1
// baseline (706.384 us; speedup 1.0000x reference)
//
#include <hip/hip_runtime.h>
#include <hip/hip_fp16.h>
#include <math.h>

typedef _Float16 half_t;
typedef half_t half4_t __attribute__((ext_vector_type(4)));
typedef half_t half8_t __attribute__((ext_vector_type(8)));
typedef float f32x4 __attribute__((ext_vector_type(4)));

#define LN_EPS 1e-5f

// ---------------------------------------------------------------------------
// Pack W0[512][768], W1[256][512], W2[128][256] (fp32 row-major) into f16
// MFMA B-fragment order:
//   packed[((cbg*T + t)*64 + l)*8 + j] = (f16) W[16*cbg + (l&15)][32*t + 8*(l>>4) + j]
// so the GEMM B-load is one contiguous 16B load per lane.
// Slot counts: W0: 32cb*24t*64 = 49152, W1: 16*16*64 = 16384, W2: 8*8*64 = 4096.
// ---------------------------------------------------------------------------
__global__ void pack_weights(const float* __restrict__ W0,
                             const float* __restrict__ W1,
                             const float* __restrict__ W2,
                             half_t* __restrict__ ws) {
    int sid = blockIdx.x * 256 + threadIdx.x;   // one 8-half slot per thread
    const float* W; int K, T, off;
    if (sid < 49152)      { W = W0; K = 768; T = 24; off = 0; }
    else if (sid < 65536) { W = W1; K = 512; T = 16; off = 49152; sid -= 49152; }
    else if (sid < 69632) { W = W2; K = 256; T = 8;  off = 65536; sid -= 65536; }
    else return;
    const int l   = sid & 63;
    const int t   = (sid >> 6) % T;
    const int cbg = (sid >> 6) / T;
    const int n   = (l & 15) + 16 * cbg;
    const int k0  = 32 * t + 8 * (l >> 4);
    const float* src = W + (size_t)n * K + k0;
    half8_t v;
    #pragma unroll
    for (int jq = 0; jq < 8; jq++) v[jq] = (half_t)src[jq];
    *(half8_t*)(ws + (size_t)(off + sid) * 8) = v;
}

// ---------------------------------------------------------------------------
// Fused MLP: 64 rows per block, 512 threads (8 waves), wave w owns 64 output
// cols of layer0 (4 col-blocks), 32 of layer1, 16 of layer2.
// ---------------------------------------------------------------------------
__global__ __launch_bounds__(512, 4)
void fused_mlp(const float* __restrict__ x_in,
               const float* __restrict__ g0, const float* __restrict__ b0, const float* __restrict__ c0,
               const float* __restrict__ g1, const float* __restrict__ b1, const float* __restrict__ c1,
               const float* __restrict__ g2, const float* __restrict__ b2, const float* __restrict__ c2,
               const float* __restrict__ g3, const float* __restrict__ b3,
               const float* __restrict__ W3, const float* __restrict__ c3,
               const half_t* __restrict__ W0p, const half_t* __restrict__ W1p, const half_t* __restrict__ W2p,
               float* __restrict__ out)
{
    __shared__ half_t frag[32768];     // 64 KiB activation-fragment buffer (reused per GEMM)
    __shared__ float psum[8][64];
    __shared__ float psq [8][64];
    __shared__ float row_m[64];
    __shared__ float row_rs[64];

    const int tid  = threadIdx.x;
    const int lane = tid & 63;
    const int wv   = tid >> 6;        // wave 0..7
    const int row  = tid >> 3;        // 0..63 (staging row)
    const int jj   = tid & 7;         // 8 threads per row
    const int grp  = lane >> 4;       // 0..3
    const int cl   = lane & 15;
    const long r0  = (long)blockIdx.x * 64;
    const float* xrow = x_in + (r0 + row) * 768;

    // ---- Phase A: LN0 stats, coalesced streaming read ----
    float s = 0.f, ss = 0.f;
    #pragma unroll 8
    for (int i = 0; i < 24; i++) {
        const float4 v = *(const float4*)(xrow + 4 * jj + 32 * i);
        s  += v.x + v.y + v.z + v.w;
        ss += v.x * v.x + v.y * v.y + v.z * v.z + v.w * v.w;
    }
    s  += __shfl_xor(s, 1);  s  += __shfl_xor(s, 2);  s  += __shfl_xor(s, 4);
    ss += __shfl_xor(ss, 1); ss += __shfl_xor(ss, 2); ss += __shfl_xor(ss, 4);
    const float m0  = s * (1.f / 768.f);
    const float rs0 = 1.f / sqrtf(ss * (1.f / 768.f) - m0 * m0 + LN_EPS);

    // ---- Layer 0 GEMM (K=768, split in 2 halves of 12 k-steps) ----
    f32x4 acc[4][4];
    #pragma unroll
    for (int rb = 0; rb < 4; rb++)
        #pragma unroll
        for (int cb = 0; cb < 4; cb++) acc[rb][cb] = 0.f;

    const int rb_w   = row >> 4;
    const int slot_w = (row & 15) + 16 * (jj >> 1);
    const int jo     = 4 * (jj & 1);

    for (int h = 0; h < 2; h++) {
        // stage normalized f16 fragments for this K-half (re-read x: L2/L3-hot)
        #pragma unroll 4
        for (int ii = 0; ii < 12; ii++) {
            const int k = 4 * jj + 32 * (12 * h + ii);
            const float4 v  = *(const float4*)(xrow + k);
            const float4 gv = *(const float4*)(g0 + k);
            const float4 bv = *(const float4*)(b0 + k);
            half4_t hv;
            hv[0] = (half_t)((v.x - m0) * rs0 * gv.x + bv.x);
            hv[1] = (half_t)((v.y - m0) * rs0 * gv.y + bv.y);
            hv[2] = (half_t)((v.z - m0) * rs0 * gv.z + bv.z);
            hv[3] = (half_t)((v.w - m0) * rs0 * gv.w + bv.w);
            *(half4_t*)(&frag[((ii * 4 + rb_w) * 64 + slot_w) * 8 + jo]) = hv;
        }
        __syncthreads();
        for (int tt = 0; tt < 12; tt++) {
            const int t = 12 * h + tt;
            half8_t af[4], bf[4];
            #pragma unroll
            for (int rb = 0; rb < 4; rb++)
                af[rb] = *(half8_t*)(&frag[((tt * 4 + rb) * 64 + lane) * 8]);
            #pragma unroll
            for (int cb = 0; cb < 4; cb++)
                bf[cb] = *(const half8_t*)(W0p + (size_t)(((4 * wv + cb) * 24 + t) * 64 + lane) * 8);
            #pragma unroll
            for (int cb = 0; cb < 4; cb++)
                #pragma unroll
                for (int rb = 0; rb < 4; rb++)
                    acc[rb][cb] = __builtin_amdgcn_mfma_f32_16x16x32_f16(af[rb], bf[cb], acc[rb][cb], 0, 0, 0);
        }
        __syncthreads();
    }

    // ---- layer0 bias + ELU + LN1 stats ----
    #pragma unroll
    for (int cb = 0; cb < 4; cb++) {
        const float cv = c0[cl + 16 * (4 * wv + cb)];
        #pragma unroll
        for (int rb = 0; rb < 4; rb++)
            #pragma unroll
            for (int v = 0; v < 4; v++) {
                float y = acc[rb][cb][v] + cv;
                acc[rb][cb][v] = y > 0.f ? y : expm1f(y);
            }
    }
    #pragma unroll
    for (int rb = 0; rb < 4; rb++)
        #pragma unroll
        for (int v = 0; v < 4; v++) {
            float a_ = 0.f, q_ = 0.f;
            #pragma unroll
            for (int cb = 0; cb < 4; cb++) { const float y = acc[rb][cb][v]; a_ += y; q_ += y * y; }
            #pragma unroll
            for (int mm = 1; mm < 16; mm <<= 1) { a_ += __shfl_xor(a_, mm); q_ += __shfl_xor(q_, mm); }
            if (cl == 0) { psum[wv][16 * rb + 4 * grp + v] = a_; psq[wv][16 * rb + 4 * grp + v] = q_; }
        }
    __syncthreads();
    if (tid < 64) {
        float a_ = 0.f, q_ = 0.f;
        #pragma unroll
        for (int wq = 0; wq < 8; wq++) { a_ += psum[wq][tid]; q_ += psq[wq][tid]; }
        const float mm = a_ * (1.f / 512.f);
        row_m[tid] = mm;
        row_rs[tid] = 1.f / sqrtf(q_ * (1.f / 512.f) - mm * mm + LN_EPS);
    }
    __syncthreads();

    // ---- write x1 fragments ----
    #pragma unroll
    for (int cb = 0; cb < 4; cb++) {
        const int c = cl + 16 * (4 * wv + cb);
        const float gv = g1[c], bv = b1[c];
        #pragma unroll
        for (int rb = 0; rb < 4; rb++)
            #pragma unroll
            for (int v = 0; v < 4; v++) {
                const int r = 16 * rb + 4 * grp + v;
                const float val = (acc[rb][cb][v] - row_m[r]) * row_rs[r] * gv + bv;
                frag[(((c >> 5) * 4 + (r >> 4)) * 64 + ((r & 15) + 16 * ((c >> 3) & 3))) * 8 + (c & 7)] = (half_t)val;
            }
    }
    __syncthreads();

    // ---- Layer 1 GEMM (K=512, 16 k-steps), wave owns 32 cols ----
    f32x4 acc1[4][2];
    #pragma unroll
    for (int rb = 0; rb < 4; rb++) { acc1[rb][0] = 0.f; acc1[rb][1] = 0.f; }
    for (int t = 0; t < 16; t++) {
        half8_t af[4], bf[2];
        #pragma unroll
        for (int rb = 0; rb < 4; rb++)
            af[rb] = *(half8_t*)(&frag[((t * 4 + rb) * 64 + lane) * 8]);
        #pragma unroll
        for (int cb = 0; cb < 2; cb++)
            bf[cb] = *(const half8_t*)(W1p + (size_t)(((2 * wv + cb) * 16 + t) * 64 + lane) * 8);
        #pragma unroll
        for (int cb = 0; cb < 2; cb++)
            #pragma unroll
            for (int rb = 0; rb < 4; rb++)
                acc1[rb][cb] = __builtin_amdgcn_mfma_f32_16x16x32_f16(af[rb], bf[cb], acc1[rb][cb], 0, 0, 0);
    }

    // ---- layer1 bias + ELU + LN2 stats ----
    #pragma unroll
    for (int cb = 0; cb < 2; cb++) {
        const float cv = c1[cl + 16 * (2 * wv + cb)];
        #pragma unroll
        for (int rb = 0; rb < 4; rb++)
            #pragma unroll
            for (int v = 0; v < 4; v++) {
                float y = acc1[rb][cb][v] + cv;
                acc1[rb][cb][v] = y > 0.f ? y : expm1f(y);
            }
    }
    #pragma unroll
    for (int rb = 0; rb < 4; rb++)
        #pragma unroll
        for (int v = 0; v < 4; v++) {
            float a_ = 0.f, q_ = 0.f;
            #pragma unroll
            for (int cb = 0; cb < 2; cb++) { const float y = acc1[rb][cb][v]; a_ += y; q_ += y * y; }
            #pragma unroll
            for (int mm = 1; mm < 16; mm <<= 1) { a_ += __shfl_xor(a_, mm); q_ += __shfl_xor(q_, mm); }
            if (cl == 0) { psum[wv][16 * rb + 4 * grp + v] = a_; psq[wv][16 * rb + 4 * grp + v] = q_; }
        }
    __syncthreads();
    if (tid < 64) {
        float a_ = 0.f, q_ = 0.f;
        #pragma unroll
        for (int wq = 0; wq < 8; wq++) { a_ += psum[wq][tid]; q_ += psq[wq][tid]; }
        const float mm = a_ * (1.f / 256.f);
        row_m[tid] = mm;
        row_rs[tid] = 1.f / sqrtf(q_ * (1.f / 256.f) - mm * mm + LN_EPS);
    }
    __syncthreads();

    // ---- write x2 fragments ----
    #pragma unroll
    for (int cb = 0; cb < 2; cb++) {
        const int c = cl + 16 * (2 * wv + cb);
        const float gv = g2[c], bv = b2[c];
        #pragma unroll
        for (int rb = 0; rb < 4; rb++)
            #pragma unroll
            for (int v = 0; v < 4; v++) {
                const int r = 16 * rb + 4 * grp + v;
                const float val = (acc1[rb][cb][v] - row_m[r]) * row_rs[r] * gv + bv;
                frag[(((c >> 5) * 4 + (r >> 4)) * 64 + ((r & 15) + 16 * ((c >> 3) & 3))) * 8 + (c & 7)] = (half_t)val;
            }
    }
    __syncthreads();

    // ---- Layer 2 GEMM (K=256, 8 k-steps), wave owns 16 cols ----
    f32x4 acc2[4];
    #pragma unroll
    for (int rb = 0; rb < 4; rb++) acc2[rb] = 0.f;
    for (int t = 0; t < 8; t++) {
        half8_t af[4], bf;
        #pragma unroll
        for (int rb = 0; rb < 4; rb++)
            af[rb] = *(half8_t*)(&frag[((t * 4 + rb) * 64 + lane) * 8]);
        bf = *(const half8_t*)(W2p + (size_t)((wv * 8 + t) * 64 + lane) * 8);
        #pragma unroll
        for (int rb = 0; rb < 4; rb++)
            acc2[rb] = __builtin_amdgcn_mfma_f32_16x16x32_f16(af[rb], bf, acc2[rb], 0, 0, 0);
    }

    // ---- layer2 bias + ELU + LN3 stats ----
    const int c2i = cl + 16 * wv;
    {
        const float cv = c2[c2i];
        #pragma unroll
        for (int rb = 0; rb < 4; rb++)
            #pragma unroll
            for (int v = 0; v < 4; v++) {
                float y = acc2[rb][v] + cv;
                acc2[rb][v] = y > 0.f ? y : expm1f(y);
            }
    }
    #pragma unroll
    for (int rb = 0; rb < 4; rb++)
        #pragma unroll
        for (int v = 0; v < 4; v++) {
            float a_ = acc2[rb][v], q_ = a_ * a_;
            #pragma unroll
            for (int mm = 1; mm < 16; mm <<= 1) { a_ += __shfl_xor(a_, mm); q_ += __shfl_xor(q_, mm); }
            if (cl == 0) { psum[wv][16 * rb + 4 * grp + v] = a_; psq[wv][16 * rb + 4 * grp + v] = q_; }
        }
    __syncthreads();
    if (tid < 64) {
        float a_ = 0.f, q_ = 0.f;
        #pragma unroll
        for (int wq = 0; wq < 8; wq++) { a_ += psum[wq][tid]; q_ += psq[wq][tid]; }
        const float mm = a_ * (1.f / 128.f);
        row_m[tid] = mm;
        row_rs[tid] = 1.f / sqrtf(q_ * (1.f / 128.f) - mm * mm + LN_EPS);
    }
    __syncthreads();

    // ---- Layer 3: LN3-normalize and dot with W3 (fp32 VALU) ----
    {
        const float g3v = g3[c2i], b3v = b3[c2i], w3v = W3[c2i];
        #pragma unroll
        for (int rb = 0; rb < 4; rb++)
            #pragma unroll
            for (int v = 0; v < 4; v++) {
                const int r = 16 * rb + 4 * grp + v;
                float pd = ((acc2[rb][v] - row_m[r]) * row_rs[r] * g3v + b3v) * w3v;
                #pragma unroll
                for (int mm = 1; mm < 16; mm <<= 1) pd += __shfl_xor(pd, mm);
                if (cl == 0) psum[wv][r] = pd;
            }
    }
    __syncthreads();
    if (tid < 64) {
        float a_ = c3[0];
        #pragma unroll
        for (int wq = 0; wq < 8; wq++) a_ += psum[wq][tid];
        out[r0 + tid] = a_;
    }
}

extern "C" void kernel_launch(void* const* d_in, const int* in_sizes, int n_in,
                              void* d_out, int out_size, void* d_ws, size_t ws_size,
                              hipStream_t stream) {
    const float* x  = (const float*)d_in[0];
    const float* g0 = (const float*)d_in[1];
    const float* b0 = (const float*)d_in[2];
    const float* W0 = (const float*)d_in[3];
    const float* c0 = (const float*)d_in[4];
    const float* g1 = (const float*)d_in[5];
    const float* b1 = (const float*)d_in[6];
    const float* W1 = (const float*)d_in[7];
    const float* c1 = (const float*)d_in[8];
    const float* g2 = (const float*)d_in[9];
    const float* b2 = (const float*)d_in[10];
    const float* W2 = (const float*)d_in[11];
    const float* c2 = (const float*)d_in[12];
    const float* g3 = (const float*)d_in[13];
    const float* b3 = (const float*)d_in[14];
    const float* W3 = (const float*)d_in[15];
    const float* c3 = (const float*)d_in[16];

    half_t* ws = (half_t*)d_ws;   // W0p: 393216 halves, W1p: 131072, W2p: 32768

    pack_weights<<<272, 256, 0, stream>>>(W0, W1, W2, ws);

    const int nrows = in_sizes[0] / 768;   // 262144
    fused_mlp<<<nrows / 64, 512, 0, stream>>>(
        x, g0, b0, c0, g1, b1, c1, g2, b2, c2, g3, b3, W3, c3,
        ws, ws + 393216, ws + 524288, (float*)d_out);
}